// Round 15
// baseline (132.187 us; speedup 1.0000x reference)
//
#include <hip/hip_runtime.h>
#include <hip/hip_bf16.h>
#include <stdint.h>

static constexpr int M = 4096, N = 4096, K = 4096;
static constexpr float FP8_MAX = 448.0f;

using f32x16 = __attribute__((ext_vector_type(16))) float;
using i32x4  = __attribute__((ext_vector_type(4))) int;
using i32x8  = __attribute__((ext_vector_type(8))) int;

// ---------------- ws layout ----------------
static constexpr size_t AQ_OFF   = 0;
static constexpr size_t BQ_OFF   = (size_t)M * K;
static constexpr size_t AMAX_OFF = BQ_OFF + (size_t)N * K;

// ---------------- amax reduction ----------------
__global__ __launch_bounds__(256) void amax_kernel(const float* __restrict__ x,
                                                   const float* __restrict__ w,
                                                   float* __restrict__ amax,
                                                   int n4_per_tensor,
                                                   int blocks_per_tensor) {
    const int tensor = blockIdx.x / blocks_per_tensor;
    const int blk    = blockIdx.x % blocks_per_tensor;
    const float4* src = (const float4*)(tensor == 0 ? x : w);

    float m = 0.0f;
    for (int i = blk * blockDim.x + threadIdx.x; i < n4_per_tensor;
         i += blocks_per_tensor * blockDim.x) {
        float4 v = src[i];
        m = fmaxf(m, fmaxf(fmaxf(fabsf(v.x), fabsf(v.y)),
                           fmaxf(fabsf(v.z), fabsf(v.w))));
    }
    #pragma unroll
    for (int off = 32; off >= 1; off >>= 1)
        m = fmaxf(m, __shfl_xor(m, off, 64));

    __shared__ float sm[4];
    const int lane = threadIdx.x & 63, wid = threadIdx.x >> 6;
    if (lane == 0) sm[wid] = m;
    __syncthreads();
    if (threadIdx.x == 0) {
        m = fmaxf(fmaxf(sm[0], sm[1]), fmaxf(sm[2], sm[3]));
        atomicMax((unsigned int*)&amax[tensor], __float_as_uint(m));
    }
}

// ---------------- quantize to fp8 e4m3fn (8 floats / thread) ----------------
__global__ __launch_bounds__(256) void quant_kernel(const float* __restrict__ x,
                                                    const float* __restrict__ w,
                                                    unsigned char* __restrict__ aq,
                                                    unsigned char* __restrict__ bq,
                                                    const float* __restrict__ amax,
                                                    int n8_per_tensor) {
    int gid = blockIdx.x * blockDim.x + threadIdx.x;
    const int tensor = (gid >= n8_per_tensor) ? 1 : 0;
    const int i = tensor ? gid - n8_per_tensor : gid;   // 8-float unit index

    const float inv = fmaxf(amax[tensor], 1e-12f) / FP8_MAX;
    const float4* src = (const float4*)(tensor == 0 ? x : w);
    int2* dst = (int2*)(tensor == 0 ? aq : bq);

    float4 v0 = src[i * 2 + 0];
    float4 v1 = src[i * 2 + 1];
    // IEEE division to bitwise-match the reference's x / inv_scale
    int p0 = __builtin_amdgcn_cvt_pk_fp8_f32(v0.x / inv, v0.y / inv, 0, false);
    p0     = __builtin_amdgcn_cvt_pk_fp8_f32(v0.z / inv, v0.w / inv, p0, true);
    int p1 = __builtin_amdgcn_cvt_pk_fp8_f32(v1.x / inv, v1.y / inv, 0, false);
    p1     = __builtin_amdgcn_cvt_pk_fp8_f32(v1.z / inv, v1.w / inv, p1, true);
    dst[i] = make_int2(p0, p1);
}

// ---------------- fp8 GEMM: 256^2, DEPTH-4 ring, read-order pipeline -------
// C[m][n] = sum_k Aq[m][k]*Bq[n][k];  out = C*scale + bias[n]
// 8 waves (2M x 4N), each 128x64 via 4x2 of 32x32; MX mfma 32x32x64, unit
// E8M0 scales (math == non-scaled fp8).
//
// Per tile (ONE barrier; no explicit lgkm drain before MFMA):
//   vmcnt(8)         [tile t's 4 DMA landed: 12 outstanding, drain 4 oldest]
//   s_barrier        [tile t published; slot (t-1)&3 free (trailing
//                     lgkmcnt(0) of iter t-1 preceded this barrier)]
//   reads b0,b1,a0..a3 (12 ds_read_b128, B FIRST), then STAGE(t+3)
//   MFMA in consume order a0b0,a0b1,a1b0,... -> compiler emits counted
//     lgkmcnt(6) before the FIRST mfma (reads 1-6 = b0,b1,a0); the
//     remaining 6 reads complete on the LDS pipe UNDER the first MFMAs.
//     (R4/R7 ordered A-first / drained fully -> near-lgkmcnt(0) stall.)
//   lgkmcnt(0)+sched_barrier  [rule 18: reads done before next restage]
static constexpr int BM = 256, BN = 256, BK = 64, DEPTH = 4, NT = K / BK;

__device__ __forceinline__ void gld_lds16(const void* g, void* l) {
    __builtin_amdgcn_global_load_lds(
        (const __attribute__((address_space(1))) void*)g,
        (__attribute__((address_space(3))) void*)l, 16, 0, 0);
}

__global__ __launch_bounds__(512, 2) void gemm_kernel(const unsigned char* __restrict__ Aq,
                                                      const unsigned char* __restrict__ Bq,
                                                      const float* __restrict__ amax,
                                                      const float* __restrict__ bias,
                                                      float* __restrict__ out) {
    __shared__ unsigned char lds[DEPTH][2][BM * BK];   // 128 KiB

    const int tid  = threadIdx.x;
    const int lane = tid & 63;
    const int w    = tid >> 6;            // 0..7
    const int wr   = w >> 2, wc = w & 3;  // 2M x 4N waves, 128x64 each

    // XCD-aware swizzle (grid 256, bijective since 256 % 8 == 0)
    const int bid = blockIdx.x;
    const int swz = (bid & 7) * 32 + (bid >> 3);
    const int brow = (swz >> 4) * BM;
    const int bcol = (swz & 15) * BN;

    const float sx = fmaxf(amax[0], 1e-12f) / FP8_MAX;
    const float sw = fmaxf(amax[1], 1e-12f) / FP8_MAX;
    const float scale = sx * sw;

    // ---- staging addresses (pre-swizzled global chunk, linear LDS dest) ----
    const int r4    = lane >> 2;
    const int row0  = w * 16 + r4;
    const int chk   = ((lane & 3) ^ ((row0 >> 1) & 3)) * 16;
    const unsigned char* Abase = Aq + (size_t)brow * K;
    const unsigned char* Bbase = Bq + (size_t)bcol * K;

    // ---- fragment read offsets (32x32x64: row=lane&31, k=(lane>>5)*32) ----
    const int frow = lane & 31;
    const int swzr = (frow >> 1) & 3;
    const int c0   = (lane >> 5) * 2;
    const int off0 = ((c0 ^ swzr) << 4);
    const int off1 = (((c0 + 1) ^ swzr) << 4);

    f32x16 acc[4][2] = {};

#define STAGE(t, d)                                                                            \
    do {                                                                                       \
        const size_t _k0 = (size_t)(t) * BK;                                                   \
        gld_lds16(Abase + (size_t)row0 * K + _k0 + chk,         &lds[d][0][w * 1024]);         \
        gld_lds16(Abase + (size_t)(row0 + 128) * K + _k0 + chk, &lds[d][0][8192 + w * 1024]);  \
        gld_lds16(Bbase + (size_t)row0 * K + _k0 + chk,         &lds[d][1][w * 1024]);         \
        gld_lds16(Bbase + (size_t)(row0 + 128) * K + _k0 + chk, &lds[d][1][8192 + w * 1024]);  \
    } while (0)

#define READ_FRAG(F, base_row, rs, ab)                                         \
    do {                                                                       \
        const unsigned char* _p = &lds[rs][ab][((base_row) + frow) * BK];      \
        i32x4 _lo = *(const i32x4*)(_p + off0);                                \
        i32x4 _hi = *(const i32x4*)(_p + off1);                                \
        F = __builtin_shufflevector(_lo, _hi, 0, 1, 2, 3, 4, 5, 6, 7);         \
    } while (0)

#define MXMFMA(a, b, c) \
    __builtin_amdgcn_mfma_scale_f32_32x32x64_f8f6f4((a), (b), (c), 0, 0, 0, 0x7F, 0, 0x7F)

#define ITER(t, rs, ss)                                                        \
    do {                                                                       \
        asm volatile("s_waitcnt vmcnt(8)" ::: "memory");                       \
        __builtin_amdgcn_s_barrier();                                          \
        __builtin_amdgcn_sched_barrier(0);                                     \
        i32x8 _b0, _b1, _a0, _a1, _a2, _a3;                                    \
        READ_FRAG(_b0, wc * 64 +  0, rs, 1);   /* reads 1-2  */                \
        READ_FRAG(_b1, wc * 64 + 32, rs, 1);   /* reads 3-4  */                \
        READ_FRAG(_a0, wr * 128 +  0, rs, 0);  /* reads 5-6  */                \
        READ_FRAG(_a1, wr * 128 + 32, rs, 0);  /* reads 7-8  */                \
        READ_FRAG(_a2, wr * 128 + 64, rs, 0);  /* reads 9-10 */                \
        READ_FRAG(_a3, wr * 128 + 96, rs, 0);  /* reads 11-12*/                \
        STAGE(((t) + 3 < NT) ? (t) + 3 : NT - 1, ss);                          \
        __builtin_amdgcn_s_setprio(1);                                         \
        acc[0][0] = MXMFMA(_a0, _b0, acc[0][0]);  /* waits lgkmcnt(6) */       \
        acc[0][1] = MXMFMA(_a0, _b1, acc[0][1]);                               \
        acc[1][0] = MXMFMA(_a1, _b0, acc[1][0]);                               \
        acc[1][1] = MXMFMA(_a1, _b1, acc[1][1]);                               \
        acc[2][0] = MXMFMA(_a2, _b0, acc[2][0]);                               \
        acc[2][1] = MXMFMA(_a2, _b1, acc[2][1]);                               \
        acc[3][0] = MXMFMA(_a3, _b0, acc[3][0]);                               \
        acc[3][1] = MXMFMA(_a3, _b1, acc[3][1]);                               \
        __builtin_amdgcn_s_setprio(0);                                         \
        asm volatile("s_waitcnt lgkmcnt(0)" ::: "memory");                     \
        __builtin_amdgcn_sched_barrier(0);                                     \
    } while (0)

    // prologue: tiles 0,1,2 -> slots 0,1,2
    STAGE(0, 0);
    STAGE(1, 1);
    STAGE(2, 2);

    for (int t = 0; t < NT; t += 4) {
        ITER(t + 0, 0, 3);
        ITER(t + 1, 1, 0);
        ITER(t + 2, 2, 1);
        ITER(t + 3, 3, 2);
    }
#undef ITER
#undef MXMFMA
#undef READ_FRAG
#undef STAGE

    // epilogue.  32x32 C/D: col=lane&31, row=(reg&3)+8*(reg>>2)+4*(lane>>5)
    #pragma unroll
    for (int mt = 0; mt < 4; ++mt) {
        const int rbase = brow + wr * 128 + mt * 32 + 4 * (lane >> 5);
        #pragma unroll
        for (int nt2 = 0; nt2 < 2; ++nt2) {
            const int col = bcol + wc * 64 + nt2 * 32 + (lane & 31);
            const float b = bias[col];
            #pragma unroll
            for (int reg = 0; reg < 16; ++reg) {
                const int row = rbase + (reg & 3) + 8 * (reg >> 2);
                out[(size_t)row * N + col] = acc[mt][nt2][reg] * scale + b;
            }
        }
    }
}

extern "C" void kernel_launch(void* const* d_in, const int* in_sizes, int n_in,
                              void* d_out, int out_size, void* d_ws, size_t ws_size,
                              hipStream_t stream) {
    const float* x    = (const float*)d_in[0];   // [4,1024,4096] f32 -> [4096][4096]
    const float* w    = (const float*)d_in[1];   // [4096][4096] f32
    const float* bias = (const float*)d_in[2];   // [4096] f32
    float* out = (float*)d_out;

    unsigned char* aq = (unsigned char*)d_ws + AQ_OFF;
    unsigned char* bq = (unsigned char*)d_ws + BQ_OFF;
    float* amax = (float*)((unsigned char*)d_ws + AMAX_OFF);

    hipMemsetAsync(amax, 0, 2 * sizeof(float), stream);  // capturable async memset

    const int n4 = (M * K) / 4;
    const int blocks_per_tensor = 512;
    amax_kernel<<<2 * blocks_per_tensor, 256, 0, stream>>>(x, w, amax, n4, blocks_per_tensor);

    const int n8 = (M * K) / 8;                  // 8 floats per thread
    const int quant_blocks = (2 * n8) / 256;     // 16384 blocks
    quant_kernel<<<quant_blocks, 256, 0, stream>>>(x, w, aq, bq, amax, n8);

    gemm_kernel<<<256, 512, 0, stream>>>(aq, bq, amax, bias, out);
}